// Round 2
// baseline (247.988 us; speedup 1.0000x reference)
//
#include <hip/hip_runtime.h>

// Problem constants (fixed by setup_inputs in the reference)
#define S_SPK 2
#define B_BATCH 4
#define M_MIC 4
#define W_TAP 3
#define F_FREQ 257
#define T_TIME 512
#define C_CH 4
#define FT (F_FREQ * T_TIME)      // 131584

// 4-byte-aligned vector types: mix window loads are only dword-aligned.
typedef float float4u __attribute__((ext_vector_type(4), aligned(4)));
typedef float float2a __attribute__((ext_vector_type(2), aligned(8)));

// ws layout: float L[S][S][B]  index (so*S_SPK + st)*B_BATCH + b  -> 16 floats

__global__ void zero_ws_kernel(float* ws) {
    if (threadIdx.x < 16) ws[threadIdx.x] = 0.0f;
}

// Grid (65, 16): x = f-group (4 f per block, one per wave), y = sb*2 + half.
// Each wave: one f-row, one t-half (256 t) = 2 chunks of 128 t.
// Lane covers t0 = half*256 + chunk*128 + 2*lane .. +1  -> mask float4 loads are
// lane-stride-16B (perfectly coalesced); mix window [t0-1..t0+2] is one
// dword-aligned float4 per mic per re/im (overlapping lanes, L1-served).
__global__ __launch_bounds__(256, 4) void pit_main_kernel(
    const float* __restrict__ masks,   // [S,B,M,W,F,T,2]
    const float* __restrict__ mixr,    // [S,B,M,F,T]
    const float* __restrict__ mixi,    // [S,B,M,F,T]
    const float* __restrict__ tgtr,    // [S,B,C,F,T] (use c=0)
    const float* __restrict__ tgti,    // [S,B,C,F,T]
    float* __restrict__ ws)
{
    const int sb   = blockIdx.y >> 1;       // so*B + b
    const int h    = blockIdx.y & 1;        // t-half
    const int so   = sb >> 2;
    const int b    = sb & 3;
    const int wave = threadIdx.x >> 6;
    const int lane = threadIdx.x & 63;
    const int f    = blockIdx.x * 4 + wave; // one f-row per wave

    float L0 = 0.0f, L1 = 0.0f;

    if (f < F_FREQ) {
        const long rowBase = (long)f * T_TIME;
        const long mixSB   = (long)sb * M_MIC * FT + rowBase;
        const long mskSB   = (long)sb * M_MIC;

        #pragma unroll
        for (int c = 0; c < 2; ++c) {
            const int t0 = h * 256 + c * 128 + (lane << 1);

            // ---- mix window wv[m][k] = mix[m][f][t0-1+k], k=0..3 ----
            int tc = t0 - 1;
            tc = tc < 0 ? 0 : tc;
            tc = tc > (T_TIME - 4) ? (T_TIME - 4) : tc;

            float4u wr[M_MIC], wi[M_MIC];
            #pragma unroll
            for (int m = 0; m < M_MIC; ++m) {
                const float* mr = mixr + mixSB + (long)m * FT;
                const float* mi = mixi + mixSB + (long)m * FT;
                float4u r = *(const float4u*)(mr + tc);
                float4u i = *(const float4u*)(mi + tc);
                if (t0 == 0) {                 // loaded [0..3], want [pad,0,1,2]
                    r[3] = r[2]; r[2] = r[1]; r[1] = r[0]; r[0] = 0.0f;
                    i[3] = i[2]; i[2] = i[1]; i[1] = i[0]; i[0] = 0.0f;
                } else if (t0 == T_TIME - 2) { // loaded [508..511], want [509,510,511,pad]
                    r[0] = r[1]; r[1] = r[2]; r[2] = r[3]; r[3] = 0.0f;
                    i[0] = i[1]; i[1] = i[2]; i[2] = i[3]; i[3] = 0.0f;
                }
                wr[m] = r; wi[m] = i;
            }

            // ---- filtering MAC: 12 coalesced mask float4 loads ----
            float or0 = 0.f, oi0 = 0.f, or1 = 0.f, oi1 = 0.f;
            #pragma unroll
            for (int m = 0; m < M_MIC; ++m) {
                #pragma unroll
                for (int w = 0; w < W_TAP; ++w) {
                    const float* mp = masks +
                        ((((mskSB + m) * W_TAP + w) * F_FREQ + f) * (long)T_TIME + t0) * 2;
                    const float4 q = *(const float4*)(mp);  // t0 re,im | t0+1 re,im
                    or0 += wr[m][w]     * q.x - wi[m][w]     * q.y;
                    oi0 += wr[m][w]     * q.y + wi[m][w]     * q.x;
                    or1 += wr[m][w + 1] * q.z - wi[m][w + 1] * q.w;
                    oi1 += wr[m][w + 1] * q.w + wi[m][w + 1] * q.z;
                }
            }

            // ---- targets (channel 0), both candidate speakers ----
            const long tOff  = rowBase + t0;
            const long base0 = (long)(0 * B_BATCH + b) * C_CH * FT + tOff;
            const long base1 = (long)(1 * B_BATCH + b) * C_CH * FT + tOff;
            const float2a t0r = *(const float2a*)(tgtr + base0);
            const float2a t0i = *(const float2a*)(tgti + base0);
            const float2a t1r = *(const float2a*)(tgtr + base1);
            const float2a t1i = *(const float2a*)(tgti + base1);

            const float ao0  = sqrtf(or0 * or0 + oi0 * oi0);
            const float ao1  = sqrtf(or1 * or1 + oi1 * oi1);
            const float a00  = sqrtf(t0r[0] * t0r[0] + t0i[0] * t0i[0]);
            const float a01  = sqrtf(t0r[1] * t0r[1] + t0i[1] * t0i[1]);
            const float a10  = sqrtf(t1r[0] * t1r[0] + t1i[0] * t1i[0]);
            const float a11  = sqrtf(t1r[1] * t1r[1] + t1i[1] * t1i[1]);

            L0 += fabsf(t0r[0] - or0) + fabsf(t0i[0] - oi0) + fabsf(a00 - ao0)
                + fabsf(t0r[1] - or1) + fabsf(t0i[1] - oi1) + fabsf(a01 - ao1);
            L1 += fabsf(t1r[0] - or0) + fabsf(t1i[0] - oi0) + fabsf(a10 - ao0)
                + fabsf(t1r[1] - or1) + fabsf(t1i[1] - oi1) + fabsf(a11 - ao1);
        }
    }

    // wave(64) shuffle reduction (idle waves contribute 0)
    #pragma unroll
    for (int off = 32; off > 0; off >>= 1) {
        L0 += __shfl_down(L0, off, 64);
        L1 += __shfl_down(L1, off, 64);
    }
    __shared__ float s0[4], s1[4];
    if (lane == 0) { s0[wave] = L0; s1[wave] = L1; }
    __syncthreads();
    if (threadIdx.x == 0) {
        atomicAdd(&ws[(so * S_SPK + 0) * B_BATCH + b], s0[0] + s0[1] + s0[2] + s0[3]);
        atomicAdd(&ws[(so * S_SPK + 1) * B_BATCH + b], s1[0] + s1[1] + s1[2] + s1[3]);
    }
}

__global__ void pit_final_kernel(const float* __restrict__ ws,
                                 float* __restrict__ out, int num_utts) {
    if (threadIdx.x == 0 && blockIdx.x == 0) {
        float acc = 0.0f;
        for (int b = 0; b < B_BATCH; ++b) {
            // perm (0,1): L[0][0] + L[1][1];  perm (1,0): L[0][1] + L[1][0]
            const float pid = ws[(0 * S_SPK + 0) * B_BATCH + b] + ws[(1 * S_SPK + 1) * B_BATCH + b];
            const float psw = ws[(0 * S_SPK + 1) * B_BATCH + b] + ws[(1 * S_SPK + 0) * B_BATCH + b];
            const float sc0 = 3.0f * pid / (float)S_SPK;
            const float sc1 = 3.0f * psw / (float)S_SPK;
            acc += fminf(sc0, sc1);
        }
        out[0] = acc / (float)num_utts;
    }
}

extern "C" void kernel_launch(void* const* d_in, const int* in_sizes, int n_in,
                              void* d_out, int out_size, void* d_ws, size_t ws_size,
                              hipStream_t stream) {
    const float* masks = (const float*)d_in[0];
    const float* mixr  = (const float*)d_in[1];
    const float* mixi  = (const float*)d_in[2];
    const float* tgtr  = (const float*)d_in[3];
    const float* tgti  = (const float*)d_in[4];
    // input_sizes values are never used by the reference; only its length is.
    const int num_utts = in_sizes[5];

    float* ws  = (float*)d_ws;
    float* out = (float*)d_out;

    zero_ws_kernel<<<1, 64, 0, stream>>>(ws);

    dim3 grid((F_FREQ + 3) / 4, S_SPK * B_BATCH * 2);   // (65, 16)
    pit_main_kernel<<<grid, 256, 0, stream>>>(masks, mixr, mixi, tgtr, tgti, ws);

    pit_final_kernel<<<1, 64, 0, stream>>>(ws, out, num_utts);
}

// Round 3
// 211.543 us; speedup vs baseline: 1.1723x; 1.1723x over previous
//
#include <hip/hip_runtime.h>

// Problem constants (fixed by setup_inputs in the reference)
#define S_SPK 2
#define B_BATCH 4
#define M_MIC 4
#define W_TAP 3
#define F_FREQ 257
#define T_TIME 512
#define C_CH 4
#define FT (F_FREQ * T_TIME)      // 131584

// 4-byte-aligned vector types: mix window loads are only dword-aligned.
typedef float float4u __attribute__((ext_vector_type(4), aligned(4)));
typedef float float2a __attribute__((ext_vector_type(2), aligned(8)));

// ws layout: float L[S][S][B]  index (so*S_SPK + st)*B_BATCH + b  -> 16 floats

__global__ void zero_ws_kernel(float* ws) {
    if (threadIdx.x < 16) ws[threadIdx.x] = 0.0f;
}

// Grid (65, 32): x = f-group (4 f per block, one per wave), y = sb*4 + tq.
// Each wave: one f-row, one t-quarter (128 t). Lane covers t0 = tq*128 + 2*lane.
// All 24 loads per thread are independent and issued before any use:
//   8 mix float4u (window t0-1..t0+2), 12 mask float4 (lane-stride-16B,
//   perfectly coalesced), 4 target float2. No launch_bounds min-wave clamp:
// round-2's __launch_bounds__(256,4) forced VGPR=64 -> 71 MB scratch spill.
__global__ __launch_bounds__(256) void pit_main_kernel(
    const float* __restrict__ masks,   // [S,B,M,W,F,T,2]
    const float* __restrict__ mixr,    // [S,B,M,F,T]
    const float* __restrict__ mixi,    // [S,B,M,F,T]
    const float* __restrict__ tgtr,    // [S,B,C,F,T] (use c=0)
    const float* __restrict__ tgti,    // [S,B,C,F,T]
    float* __restrict__ ws)
{
    const int sb   = blockIdx.y >> 2;       // so*B + b
    const int tq   = blockIdx.y & 3;        // t-quarter
    const int so   = sb >> 2;
    const int b    = sb & 3;
    const int wave = threadIdx.x >> 6;
    const int lane = threadIdx.x & 63;
    const int f    = blockIdx.x * 4 + wave; // one f-row per wave

    float L0 = 0.0f, L1 = 0.0f;

    if (f < F_FREQ) {
        const int t0 = tq * 128 + (lane << 1);
        const long rowBase = (long)f * T_TIME;
        const long mixSB   = (long)sb * M_MIC * FT + rowBase;
        const long mskSB   = (long)sb * M_MIC;

        // ---- issue mix window loads: wv[m][k] = mix[m][f][tc+k], k=0..3 ----
        int tc = t0 - 1;
        tc = tc < 0 ? 0 : tc;
        tc = tc > (T_TIME - 4) ? (T_TIME - 4) : tc;

        float4u wr[M_MIC], wi[M_MIC];
        #pragma unroll
        for (int m = 0; m < M_MIC; ++m) {
            wr[m] = *(const float4u*)(mixr + mixSB + (long)m * FT + tc);
            wi[m] = *(const float4u*)(mixi + mixSB + (long)m * FT + tc);
        }

        // ---- issue all 12 coalesced mask float4 loads ----
        float4 q[M_MIC * W_TAP];
        #pragma unroll
        for (int m = 0; m < M_MIC; ++m) {
            #pragma unroll
            for (int w = 0; w < W_TAP; ++w) {
                q[m * W_TAP + w] = *(const float4*)(masks +
                    ((((mskSB + m) * W_TAP + w) * F_FREQ + f) * (long)T_TIME + t0) * 2);
            }
        }

        // ---- issue target loads (channel 0), both candidate speakers ----
        const long tOff = rowBase + t0;
        const float2a t0r = *(const float2a*)(tgtr + ((long)(0 * B_BATCH + b) * C_CH) * FT + tOff);
        const float2a t0i = *(const float2a*)(tgti + ((long)(0 * B_BATCH + b) * C_CH) * FT + tOff);
        const float2a t1r = *(const float2a*)(tgtr + ((long)(1 * B_BATCH + b) * C_CH) * FT + tOff);
        const float2a t1i = *(const float2a*)(tgti + ((long)(1 * B_BATCH + b) * C_CH) * FT + tOff);

        // ---- boundary fixup on the window registers (after loads issued) ----
        if (t0 == 0) {                 // loaded [0..3], want [pad,0,1,2]
            #pragma unroll
            for (int m = 0; m < M_MIC; ++m) {
                wr[m][3] = wr[m][2]; wr[m][2] = wr[m][1]; wr[m][1] = wr[m][0]; wr[m][0] = 0.0f;
                wi[m][3] = wi[m][2]; wi[m][2] = wi[m][1]; wi[m][1] = wi[m][0]; wi[m][0] = 0.0f;
            }
        } else if (t0 == T_TIME - 2) { // loaded [508..511], want [509,510,511,pad]
            #pragma unroll
            for (int m = 0; m < M_MIC; ++m) {
                wr[m][0] = wr[m][1]; wr[m][1] = wr[m][2]; wr[m][2] = wr[m][3]; wr[m][3] = 0.0f;
                wi[m][0] = wi[m][1]; wi[m][1] = wi[m][2]; wi[m][2] = wi[m][3]; wi[m][3] = 0.0f;
            }
        }

        // ---- complex MAC over (m,w), consuming masks in load order ----
        float or0 = 0.f, oi0 = 0.f, or1 = 0.f, oi1 = 0.f;
        #pragma unroll
        for (int m = 0; m < M_MIC; ++m) {
            #pragma unroll
            for (int w = 0; w < W_TAP; ++w) {
                const float4 qq = q[m * W_TAP + w];
                or0 += wr[m][w]     * qq.x - wi[m][w]     * qq.y;
                oi0 += wr[m][w]     * qq.y + wi[m][w]     * qq.x;
                or1 += wr[m][w + 1] * qq.z - wi[m][w + 1] * qq.w;
                oi1 += wr[m][w + 1] * qq.w + wi[m][w + 1] * qq.z;
            }
        }

        // ---- loss terms ----
        const float ao0 = sqrtf(or0 * or0 + oi0 * oi0);
        const float ao1 = sqrtf(or1 * or1 + oi1 * oi1);
        const float a00 = sqrtf(t0r[0] * t0r[0] + t0i[0] * t0i[0]);
        const float a01 = sqrtf(t0r[1] * t0r[1] + t0i[1] * t0i[1]);
        const float a10 = sqrtf(t1r[0] * t1r[0] + t1i[0] * t1i[0]);
        const float a11 = sqrtf(t1r[1] * t1r[1] + t1i[1] * t1i[1]);

        L0 = fabsf(t0r[0] - or0) + fabsf(t0i[0] - oi0) + fabsf(a00 - ao0)
           + fabsf(t0r[1] - or1) + fabsf(t0i[1] - oi1) + fabsf(a01 - ao1);
        L1 = fabsf(t1r[0] - or0) + fabsf(t1i[0] - oi0) + fabsf(a10 - ao0)
           + fabsf(t1r[1] - or1) + fabsf(t1i[1] - oi1) + fabsf(a11 - ao1);
    }

    // wave(64) shuffle reduction (idle waves contribute 0)
    #pragma unroll
    for (int off = 32; off > 0; off >>= 1) {
        L0 += __shfl_down(L0, off, 64);
        L1 += __shfl_down(L1, off, 64);
    }
    __shared__ float s0[4], s1[4];
    if (lane == 0) { s0[wave] = L0; s1[wave] = L1; }
    __syncthreads();
    if (threadIdx.x == 0) {
        atomicAdd(&ws[(so * S_SPK + 0) * B_BATCH + b], s0[0] + s0[1] + s0[2] + s0[3]);
        atomicAdd(&ws[(so * S_SPK + 1) * B_BATCH + b], s1[0] + s1[1] + s1[2] + s1[3]);
    }
}

__global__ void pit_final_kernel(const float* __restrict__ ws,
                                 float* __restrict__ out, int num_utts) {
    if (threadIdx.x == 0 && blockIdx.x == 0) {
        float acc = 0.0f;
        for (int b = 0; b < B_BATCH; ++b) {
            // perm (0,1): L[0][0] + L[1][1];  perm (1,0): L[0][1] + L[1][0]
            const float pid = ws[(0 * S_SPK + 0) * B_BATCH + b] + ws[(1 * S_SPK + 1) * B_BATCH + b];
            const float psw = ws[(0 * S_SPK + 1) * B_BATCH + b] + ws[(1 * S_SPK + 0) * B_BATCH + b];
            const float sc0 = 3.0f * pid / (float)S_SPK;
            const float sc1 = 3.0f * psw / (float)S_SPK;
            acc += fminf(sc0, sc1);
        }
        out[0] = acc / (float)num_utts;
    }
}

extern "C" void kernel_launch(void* const* d_in, const int* in_sizes, int n_in,
                              void* d_out, int out_size, void* d_ws, size_t ws_size,
                              hipStream_t stream) {
    const float* masks = (const float*)d_in[0];
    const float* mixr  = (const float*)d_in[1];
    const float* mixi  = (const float*)d_in[2];
    const float* tgtr  = (const float*)d_in[3];
    const float* tgti  = (const float*)d_in[4];
    // input_sizes values are never used by the reference; only its length is.
    const int num_utts = in_sizes[5];

    float* ws  = (float*)d_ws;
    float* out = (float*)d_out;

    zero_ws_kernel<<<1, 64, 0, stream>>>(ws);

    dim3 grid((F_FREQ + 3) / 4, S_SPK * B_BATCH * 4);   // (65, 32)
    pit_main_kernel<<<grid, 256, 0, stream>>>(masks, mixr, mixi, tgtr, tgti, ws);

    pit_final_kernel<<<1, 64, 0, stream>>>(ws, out, num_utts);
}

// Round 4
// 201.448 us; speedup vs baseline: 1.2310x; 1.0501x over previous
//
#include <hip/hip_runtime.h>

// Problem constants (fixed by setup_inputs in the reference)
#define S_SPK 2
#define B_BATCH 4
#define M_MIC 4
#define W_TAP 3
#define F_FREQ 257
#define T_TIME 512
#define C_CH 4
#define FT (F_FREQ * T_TIME)      // 131584

#define NBLK_X 65                 // ceil(F/4)
#define NBLK_Y 32                 // S*B*4 t-quarters
#define NSLOT (NBLK_X * NBLK_Y)   // 2080 partial slots

// 4-byte-aligned vector types: mix window loads are only dword-aligned.
typedef float float4u __attribute__((ext_vector_type(4), aligned(4)));
typedef float float2a __attribute__((ext_vector_type(2), aligned(8)));

// ws layout: float partial[NSLOT][2]  (slot = by*NBLK_X + bx; [0]=L0, [1]=L1)
// No atomics: round 0-3 all hit a ~62-69us floor caused by ~4100 device-scope
// fp32 atomicAdds landing on ONE 64B cache line (16-float ws) from all 8 XCDs.
// Per-block stores to disjoint slots + a tiny reduction kernel replace them.

// Grid (65, 32): x = f-group (4 f per block, one per wave), y = sb*4 + tq.
// Each wave: one f-row, one t-quarter (128 t). Lane covers t0 = tq*128 + 2*lane.
__global__ __launch_bounds__(256) void pit_main_kernel(
    const float* __restrict__ masks,   // [S,B,M,W,F,T,2]
    const float* __restrict__ mixr,    // [S,B,M,F,T]
    const float* __restrict__ mixi,    // [S,B,M,F,T]
    const float* __restrict__ tgtr,    // [S,B,C,F,T] (use c=0)
    const float* __restrict__ tgti,    // [S,B,C,F,T]
    float* __restrict__ ws)
{
    const int sb   = blockIdx.y >> 2;       // so*B + b
    const int tq   = blockIdx.y & 3;        // t-quarter
    const int b    = sb & 3;
    const int wave = threadIdx.x >> 6;
    const int lane = threadIdx.x & 63;
    const int f    = blockIdx.x * 4 + wave; // one f-row per wave

    float L0 = 0.0f, L1 = 0.0f;

    if (f < F_FREQ) {
        const int t0 = tq * 128 + (lane << 1);
        const long rowBase = (long)f * T_TIME;
        const long mixSB   = (long)sb * M_MIC * FT + rowBase;
        const long mskSB   = (long)sb * M_MIC;

        // ---- issue mix window loads: wv[m][k] = mix[m][f][tc+k], k=0..3 ----
        int tc = t0 - 1;
        tc = tc < 0 ? 0 : tc;
        tc = tc > (T_TIME - 4) ? (T_TIME - 4) : tc;

        float4u wr[M_MIC], wi[M_MIC];
        #pragma unroll
        for (int m = 0; m < M_MIC; ++m) {
            wr[m] = *(const float4u*)(mixr + mixSB + (long)m * FT + tc);
            wi[m] = *(const float4u*)(mixi + mixSB + (long)m * FT + tc);
        }

        // ---- issue all 12 coalesced mask float4 loads ----
        float4 q[M_MIC * W_TAP];
        #pragma unroll
        for (int m = 0; m < M_MIC; ++m) {
            #pragma unroll
            for (int w = 0; w < W_TAP; ++w) {
                q[m * W_TAP + w] = *(const float4*)(masks +
                    ((((mskSB + m) * W_TAP + w) * F_FREQ + f) * (long)T_TIME + t0) * 2);
            }
        }

        // ---- issue target loads (channel 0), both candidate speakers ----
        const long tOff = rowBase + t0;
        const float2a t0r = *(const float2a*)(tgtr + ((long)(0 * B_BATCH + b) * C_CH) * FT + tOff);
        const float2a t0i = *(const float2a*)(tgti + ((long)(0 * B_BATCH + b) * C_CH) * FT + tOff);
        const float2a t1r = *(const float2a*)(tgtr + ((long)(1 * B_BATCH + b) * C_CH) * FT + tOff);
        const float2a t1i = *(const float2a*)(tgti + ((long)(1 * B_BATCH + b) * C_CH) * FT + tOff);

        // ---- boundary fixup on the window registers (after loads issued) ----
        if (t0 == 0) {                 // loaded [0..3], want [pad,0,1,2]
            #pragma unroll
            for (int m = 0; m < M_MIC; ++m) {
                wr[m][3] = wr[m][2]; wr[m][2] = wr[m][1]; wr[m][1] = wr[m][0]; wr[m][0] = 0.0f;
                wi[m][3] = wi[m][2]; wi[m][2] = wi[m][1]; wi[m][1] = wi[m][0]; wi[m][0] = 0.0f;
            }
        } else if (t0 == T_TIME - 2) { // loaded [508..511], want [509,510,511,pad]
            #pragma unroll
            for (int m = 0; m < M_MIC; ++m) {
                wr[m][0] = wr[m][1]; wr[m][1] = wr[m][2]; wr[m][2] = wr[m][3]; wr[m][3] = 0.0f;
                wi[m][0] = wi[m][1]; wi[m][1] = wi[m][2]; wi[m][2] = wi[m][3]; wi[m][3] = 0.0f;
            }
        }

        // ---- complex MAC over (m,w), consuming masks in load order ----
        float or0 = 0.f, oi0 = 0.f, or1 = 0.f, oi1 = 0.f;
        #pragma unroll
        for (int m = 0; m < M_MIC; ++m) {
            #pragma unroll
            for (int w = 0; w < W_TAP; ++w) {
                const float4 qq = q[m * W_TAP + w];
                or0 += wr[m][w]     * qq.x - wi[m][w]     * qq.y;
                oi0 += wr[m][w]     * qq.y + wi[m][w]     * qq.x;
                or1 += wr[m][w + 1] * qq.z - wi[m][w + 1] * qq.w;
                oi1 += wr[m][w + 1] * qq.w + wi[m][w + 1] * qq.z;
            }
        }

        // ---- loss terms ----
        const float ao0 = sqrtf(or0 * or0 + oi0 * oi0);
        const float ao1 = sqrtf(or1 * or1 + oi1 * oi1);
        const float a00 = sqrtf(t0r[0] * t0r[0] + t0i[0] * t0i[0]);
        const float a01 = sqrtf(t0r[1] * t0r[1] + t0i[1] * t0i[1]);
        const float a10 = sqrtf(t1r[0] * t1r[0] + t1i[0] * t1i[0]);
        const float a11 = sqrtf(t1r[1] * t1r[1] + t1i[1] * t1i[1]);

        L0 = fabsf(t0r[0] - or0) + fabsf(t0i[0] - oi0) + fabsf(a00 - ao0)
           + fabsf(t0r[1] - or1) + fabsf(t0i[1] - oi1) + fabsf(a01 - ao1);
        L1 = fabsf(t1r[0] - or0) + fabsf(t1i[0] - oi0) + fabsf(a10 - ao0)
           + fabsf(t1r[1] - or1) + fabsf(t1i[1] - oi1) + fabsf(a11 - ao1);
    }

    // wave(64) shuffle reduction (idle waves contribute 0)
    #pragma unroll
    for (int off = 32; off > 0; off >>= 1) {
        L0 += __shfl_down(L0, off, 64);
        L1 += __shfl_down(L1, off, 64);
    }
    __shared__ float s0[4], s1[4];
    if (lane == 0) { s0[wave] = L0; s1[wave] = L1; }
    __syncthreads();
    if (threadIdx.x == 0) {
        const int slot = blockIdx.y * NBLK_X + blockIdx.x;
        ws[slot * 2 + 0] = s0[0] + s0[1] + s0[2] + s0[3];
        ws[slot * 2 + 1] = s1[0] + s1[1] + s1[2] + s1[3];
    }
}

// One block, 256 threads: reduce NSLOT x 2 partials into L[so][st][b],
// then permutation-min. Kernel-boundary dependency makes partials coherent.
__global__ __launch_bounds__(256) void pit_final_kernel(
    const float* __restrict__ ws, float* __restrict__ out, int num_utts)
{
    float acc[16];                       // [so][st][b] = (so*2+st)*4+b
    #pragma unroll
    for (int i = 0; i < 16; ++i) acc[i] = 0.0f;

    for (int slot = threadIdx.x; slot < NSLOT; slot += 256) {
        const int y  = slot / NBLK_X;    // blockIdx.y of producer
        const int sb = y >> 2;
        const int so = sb >> 2;
        const int b  = sb & 3;
        acc[((so * 2 + 0) << 2) + b] += ws[slot * 2 + 0];
        acc[((so * 2 + 1) << 2) + b] += ws[slot * 2 + 1];
    }

    __shared__ float red[16][4];
    const int wave = threadIdx.x >> 6;
    const int lane = threadIdx.x & 63;
    #pragma unroll
    for (int i = 0; i < 16; ++i) {
        float v = acc[i];
        #pragma unroll
        for (int off = 32; off > 0; off >>= 1) v += __shfl_down(v, off, 64);
        if (lane == 0) red[i][wave] = v;
    }
    __syncthreads();

    if (threadIdx.x == 0) {
        float L[16];
        #pragma unroll
        for (int i = 0; i < 16; ++i) L[i] = red[i][0] + red[i][1] + red[i][2] + red[i][3];
        float accu = 0.0f;
        for (int b = 0; b < B_BATCH; ++b) {
            // perm (0,1): L[0][0]+L[1][1];  perm (1,0): L[0][1]+L[1][0]
            const float pid = L[(0 * 2 + 0) * 4 + b] + L[(1 * 2 + 1) * 4 + b];
            const float psw = L[(0 * 2 + 1) * 4 + b] + L[(1 * 2 + 0) * 4 + b];
            const float sc0 = 3.0f * pid / (float)S_SPK;
            const float sc1 = 3.0f * psw / (float)S_SPK;
            accu += fminf(sc0, sc1);
        }
        out[0] = accu / (float)num_utts;
    }
}

extern "C" void kernel_launch(void* const* d_in, const int* in_sizes, int n_in,
                              void* d_out, int out_size, void* d_ws, size_t ws_size,
                              hipStream_t stream) {
    const float* masks = (const float*)d_in[0];
    const float* mixr  = (const float*)d_in[1];
    const float* mixi  = (const float*)d_in[2];
    const float* tgtr  = (const float*)d_in[3];
    const float* tgti  = (const float*)d_in[4];
    // input_sizes values are never used by the reference; only its length is.
    const int num_utts = in_sizes[5];

    float* ws  = (float*)d_ws;
    float* out = (float*)d_out;

    dim3 grid(NBLK_X, NBLK_Y);   // (65, 32)
    pit_main_kernel<<<grid, 256, 0, stream>>>(masks, mixr, mixi, tgtr, tgti, ws);

    pit_final_kernel<<<1, 256, 0, stream>>>(ws, out, num_utts);
}

// Round 5
// 199.769 us; speedup vs baseline: 1.2414x; 1.0084x over previous
//
#include <hip/hip_runtime.h>

// Problem constants (fixed by setup_inputs in the reference)
#define S_SPK 2
#define B_BATCH 4
#define M_MIC 4
#define W_TAP 3
#define F_FREQ 257
#define T_TIME 512
#define C_CH 4
#define FT (F_FREQ * T_TIME)      // 131584

#define NBLK_X 33                 // ceil(F/8): 8 f per block, 2 per wave
#define NBLK_Y 32                 // S*B*4 t-quarters
#define NSLOT (NBLK_X * NBLK_Y)   // 1056 partial slots

// 4-byte-aligned vector types: mix window loads are only dword-aligned.
typedef float float4u __attribute__((ext_vector_type(4), aligned(4)));
typedef float float2a __attribute__((ext_vector_type(2), aligned(8)));

// ws layout: float partial[NSLOT][2]  (slot = by*NBLK_X + bx; [0]=L0, [1]=L1)
// Round-4 lesson: harness fill dominates top-5; main ~54us inferred.
// This round: 2 f-rows per wave -> 48 independent loads in one straight-line
// batch (no guards in the load path; f clamped, contribution zeroed by flag)
// to double per-wave bytes-in-flight and break the serial waitcnt chain.

__global__ __launch_bounds__(256) void pit_main_kernel(
    const float* __restrict__ masks,   // [S,B,M,W,F,T,2]
    const float* __restrict__ mixr,    // [S,B,M,F,T]
    const float* __restrict__ mixi,    // [S,B,M,F,T]
    const float* __restrict__ tgtr,    // [S,B,C,F,T] (use c=0)
    const float* __restrict__ tgti,    // [S,B,C,F,T]
    float* __restrict__ ws)
{
    const int sb   = blockIdx.y >> 2;       // so*B + b
    const int tq   = blockIdx.y & 3;        // t-quarter
    const int b    = sb & 3;
    const int wave = threadIdx.x >> 6;
    const int lane = threadIdx.x & 63;

    const int f0   = blockIdx.x * 8 + wave * 2;           // first f of this wave
    const int fA   = (f0     < F_FREQ) ? f0     : (F_FREQ - 1);   // clamped
    const int fB   = (f0 + 1 < F_FREQ) ? f0 + 1 : (F_FREQ - 1);
    const float vA = (f0     < F_FREQ) ? 1.0f : 0.0f;     // validity flags
    const float vB = (f0 + 1 < F_FREQ) ? 1.0f : 0.0f;

    const int t0 = tq * 128 + (lane << 1);
    int tc = t0 - 1;
    tc = tc < 0 ? 0 : tc;
    tc = tc > (T_TIME - 4) ? (T_TIME - 4) : tc;

    const long mixSB = (long)sb * M_MIC * FT;
    const long mskSB = (long)sb * M_MIC;
    const long rowA  = (long)fA * T_TIME;
    const long rowB  = (long)fB * T_TIME;

    // ---- issue all 48 loads as one straight-line batch ----
    float4u wrA[M_MIC], wiA[M_MIC], wrB[M_MIC], wiB[M_MIC];
    #pragma unroll
    for (int m = 0; m < M_MIC; ++m) {
        const float* br = mixr + mixSB + (long)m * FT;
        const float* bi = mixi + mixSB + (long)m * FT;
        wrA[m] = *(const float4u*)(br + rowA + tc);
        wiA[m] = *(const float4u*)(bi + rowA + tc);
        wrB[m] = *(const float4u*)(br + rowB + tc);
        wiB[m] = *(const float4u*)(bi + rowB + tc);
    }

    float4 qA[M_MIC * W_TAP], qB[M_MIC * W_TAP];
    #pragma unroll
    for (int m = 0; m < M_MIC; ++m) {
        #pragma unroll
        for (int w = 0; w < W_TAP; ++w) {
            const long mw = ((mskSB + m) * W_TAP + w) * F_FREQ;
            qA[m * W_TAP + w] = *(const float4*)(masks + ((mw + fA) * (long)T_TIME + t0) * 2);
            qB[m * W_TAP + w] = *(const float4*)(masks + ((mw + fB) * (long)T_TIME + t0) * 2);
        }
    }

    const long tg0 = (long)(0 * B_BATCH + b) * C_CH * FT;
    const long tg1 = (long)(1 * B_BATCH + b) * C_CH * FT;
    const float2a t0rA = *(const float2a*)(tgtr + tg0 + rowA + t0);
    const float2a t0iA = *(const float2a*)(tgti + tg0 + rowA + t0);
    const float2a t1rA = *(const float2a*)(tgtr + tg1 + rowA + t0);
    const float2a t1iA = *(const float2a*)(tgti + tg1 + rowA + t0);
    const float2a t0rB = *(const float2a*)(tgtr + tg0 + rowB + t0);
    const float2a t0iB = *(const float2a*)(tgti + tg0 + rowB + t0);
    const float2a t1rB = *(const float2a*)(tgtr + tg1 + rowB + t0);
    const float2a t1iB = *(const float2a*)(tgti + tg1 + rowB + t0);

    // ---- boundary fixup on window registers (same t0 for both f-rows) ----
    if (t0 == 0) {                 // loaded [0..3], want [pad,0,1,2]
        #pragma unroll
        for (int m = 0; m < M_MIC; ++m) {
            wrA[m][3]=wrA[m][2]; wrA[m][2]=wrA[m][1]; wrA[m][1]=wrA[m][0]; wrA[m][0]=0.f;
            wiA[m][3]=wiA[m][2]; wiA[m][2]=wiA[m][1]; wiA[m][1]=wiA[m][0]; wiA[m][0]=0.f;
            wrB[m][3]=wrB[m][2]; wrB[m][2]=wrB[m][1]; wrB[m][1]=wrB[m][0]; wrB[m][0]=0.f;
            wiB[m][3]=wiB[m][2]; wiB[m][2]=wiB[m][1]; wiB[m][1]=wiB[m][0]; wiB[m][0]=0.f;
        }
    } else if (t0 == T_TIME - 2) { // loaded [508..511], want [509,510,511,pad]
        #pragma unroll
        for (int m = 0; m < M_MIC; ++m) {
            wrA[m][0]=wrA[m][1]; wrA[m][1]=wrA[m][2]; wrA[m][2]=wrA[m][3]; wrA[m][3]=0.f;
            wiA[m][0]=wiA[m][1]; wiA[m][1]=wiA[m][2]; wiA[m][2]=wiA[m][3]; wiA[m][3]=0.f;
            wrB[m][0]=wrB[m][1]; wrB[m][1]=wrB[m][2]; wrB[m][2]=wrB[m][3]; wrB[m][3]=0.f;
            wiB[m][0]=wiB[m][1]; wiB[m][1]=wiB[m][2]; wiB[m][2]=wiB[m][3]; wiB[m][3]=0.f;
        }
    }

    // ---- complex MACs, consuming masks in load order (A and B interleaved) ----
    float orA0=0.f,oiA0=0.f,orA1=0.f,oiA1=0.f, orB0=0.f,oiB0=0.f,orB1=0.f,oiB1=0.f;
    #pragma unroll
    for (int m = 0; m < M_MIC; ++m) {
        #pragma unroll
        for (int w = 0; w < W_TAP; ++w) {
            const float4 a = qA[m * W_TAP + w];
            orA0 += wrA[m][w]     * a.x - wiA[m][w]     * a.y;
            oiA0 += wrA[m][w]     * a.y + wiA[m][w]     * a.x;
            orA1 += wrA[m][w + 1] * a.z - wiA[m][w + 1] * a.w;
            oiA1 += wrA[m][w + 1] * a.w + wiA[m][w + 1] * a.z;
            const float4 c = qB[m * W_TAP + w];
            orB0 += wrB[m][w]     * c.x - wiB[m][w]     * c.y;
            oiB0 += wrB[m][w]     * c.y + wiB[m][w]     * c.x;
            orB1 += wrB[m][w + 1] * c.z - wiB[m][w + 1] * c.w;
            oiB1 += wrB[m][w + 1] * c.w + wiB[m][w + 1] * c.z;
        }
    }

    // ---- loss terms, masked by validity ----
    float L0, L1;
    {
        const float aoA0 = sqrtf(orA0*orA0 + oiA0*oiA0);
        const float aoA1 = sqrtf(orA1*orA1 + oiA1*oiA1);
        const float a00  = sqrtf(t0rA[0]*t0rA[0] + t0iA[0]*t0iA[0]);
        const float a01  = sqrtf(t0rA[1]*t0rA[1] + t0iA[1]*t0iA[1]);
        const float a10  = sqrtf(t1rA[0]*t1rA[0] + t1iA[0]*t1iA[0]);
        const float a11  = sqrtf(t1rA[1]*t1rA[1] + t1iA[1]*t1iA[1]);
        const float l0A = fabsf(t0rA[0]-orA0)+fabsf(t0iA[0]-oiA0)+fabsf(a00-aoA0)
                        + fabsf(t0rA[1]-orA1)+fabsf(t0iA[1]-oiA1)+fabsf(a01-aoA1);
        const float l1A = fabsf(t1rA[0]-orA0)+fabsf(t1iA[0]-oiA0)+fabsf(a10-aoA0)
                        + fabsf(t1rA[1]-orA1)+fabsf(t1iA[1]-oiA1)+fabsf(a11-aoA1);

        const float aoB0 = sqrtf(orB0*orB0 + oiB0*oiB0);
        const float aoB1 = sqrtf(orB1*orB1 + oiB1*oiB1);
        const float b00  = sqrtf(t0rB[0]*t0rB[0] + t0iB[0]*t0iB[0]);
        const float b01  = sqrtf(t0rB[1]*t0rB[1] + t0iB[1]*t0iB[1]);
        const float b10  = sqrtf(t1rB[0]*t1rB[0] + t1iB[0]*t1iB[0]);
        const float b11  = sqrtf(t1rB[1]*t1rB[1] + t1iB[1]*t1iB[1]);
        const float l0B = fabsf(t0rB[0]-orB0)+fabsf(t0iB[0]-oiB0)+fabsf(b00-aoB0)
                        + fabsf(t0rB[1]-orB1)+fabsf(t0iB[1]-oiB1)+fabsf(b01-aoB1);
        const float l1B = fabsf(t1rB[0]-orB0)+fabsf(t1iB[0]-oiB0)+fabsf(b10-aoB0)
                        + fabsf(t1rB[1]-orB1)+fabsf(t1iB[1]-oiB1)+fabsf(b11-aoB1);

        L0 = vA * l0A + vB * l0B;
        L1 = vA * l1A + vB * l1B;
    }

    // wave(64) shuffle reduction
    #pragma unroll
    for (int off = 32; off > 0; off >>= 1) {
        L0 += __shfl_down(L0, off, 64);
        L1 += __shfl_down(L1, off, 64);
    }
    __shared__ float s0[4], s1[4];
    if (lane == 0) { s0[wave] = L0; s1[wave] = L1; }
    __syncthreads();
    if (threadIdx.x == 0) {
        const int slot = blockIdx.y * NBLK_X + blockIdx.x;
        ws[slot * 2 + 0] = s0[0] + s0[1] + s0[2] + s0[3];
        ws[slot * 2 + 1] = s1[0] + s1[1] + s1[2] + s1[3];
    }
}

// One block, 256 threads: reduce NSLOT x 2 partials into L[so][st][b],
// then permutation-min. Kernel-boundary dependency makes partials coherent.
__global__ __launch_bounds__(256) void pit_final_kernel(
    const float* __restrict__ ws, float* __restrict__ out, int num_utts)
{
    float acc[16];                       // [so][st][b] = (so*2+st)*4+b
    #pragma unroll
    for (int i = 0; i < 16; ++i) acc[i] = 0.0f;

    for (int slot = threadIdx.x; slot < NSLOT; slot += 256) {
        const int y  = slot / NBLK_X;    // blockIdx.y of producer
        const int sb = y >> 2;
        const int so = sb >> 2;
        const int b  = sb & 3;
        acc[((so * 2 + 0) << 2) + b] += ws[slot * 2 + 0];
        acc[((so * 2 + 1) << 2) + b] += ws[slot * 2 + 1];
    }

    __shared__ float red[16][4];
    const int wave = threadIdx.x >> 6;
    const int lane = threadIdx.x & 63;
    #pragma unroll
    for (int i = 0; i < 16; ++i) {
        float v = acc[i];
        #pragma unroll
        for (int off = 32; off > 0; off >>= 1) v += __shfl_down(v, off, 64);
        if (lane == 0) red[i][wave] = v;
    }
    __syncthreads();

    if (threadIdx.x == 0) {
        float L[16];
        #pragma unroll
        for (int i = 0; i < 16; ++i) L[i] = red[i][0] + red[i][1] + red[i][2] + red[i][3];
        float accu = 0.0f;
        for (int b = 0; b < B_BATCH; ++b) {
            // perm (0,1): L[0][0]+L[1][1];  perm (1,0): L[0][1]+L[1][0]
            const float pid = L[(0 * 2 + 0) * 4 + b] + L[(1 * 2 + 1) * 4 + b];
            const float psw = L[(0 * 2 + 1) * 4 + b] + L[(1 * 2 + 0) * 4 + b];
            const float sc0 = 3.0f * pid / (float)S_SPK;
            const float sc1 = 3.0f * psw / (float)S_SPK;
            accu += fminf(sc0, sc1);
        }
        out[0] = accu / (float)num_utts;
    }
}

extern "C" void kernel_launch(void* const* d_in, const int* in_sizes, int n_in,
                              void* d_out, int out_size, void* d_ws, size_t ws_size,
                              hipStream_t stream) {
    const float* masks = (const float*)d_in[0];
    const float* mixr  = (const float*)d_in[1];
    const float* mixi  = (const float*)d_in[2];
    const float* tgtr  = (const float*)d_in[3];
    const float* tgti  = (const float*)d_in[4];
    // input_sizes values are never used by the reference; only its length is.
    const int num_utts = in_sizes[5];

    float* ws  = (float*)d_ws;
    float* out = (float*)d_out;

    dim3 grid(NBLK_X, NBLK_Y);   // (33, 32)
    pit_main_kernel<<<grid, 256, 0, stream>>>(masks, mixr, mixi, tgtr, tgti, ws);

    pit_final_kernel<<<1, 256, 0, stream>>>(ws, out, num_utts);
}